// Round 4
// baseline (240.894 us; speedup 1.0000x reference)
//
#include <hip/hip_runtime.h>
#include <math.h>

#define NPTS 400000
#define NQUAD 100000          // NPTS/4
#define NBATCH 8
#define K_OUT 64
#define IDX_SENTINEL 0x7fffffff

// K2 geometry
#define PPW2 4096             // points per wave in topk kernel
#define K2_BLOCKS 25          // ceil(ceil(400000/4096)/4) = ceil(98/4)
#define LPB (K2_BLOCKS * 4)   // candidate lists per batch (=100)

// wbuf layout (floats): [0..511] W1^T [c][o]; [512..639] W2^T [c][o];
// [640..655] b1; [656..663] b2; [664..671] W3; [672] b3
#define WB_W2 512
#define WB_B1 640
#define WB_B2 656
#define WB_W3 664
#define WB_B3 672

// comparator: (value desc, index asc) — matches jax.lax.top_k tie-breaking
__device__ __forceinline__ bool better(float av, int ai, float bv, int bi) {
    return (av > bv) || (av == bv && ai < bi);
}

__device__ __forceinline__ void cmp_swap(float& v, int& i, int j, bool keepBetter) {
    float ov = __shfl_xor(v, j);
    int   oi = __shfl_xor(i, j);
    bool ob = better(ov, oi, v, i);
    if (keepBetter ? ob : !ob) { v = ov; i = oi; }
}

// Maintain per-wave top-64 (1 entry/lane, sorted descending by comparator).
__device__ __forceinline__ void wave_topk_insert(float& bv, int& bi, float nv, int ni, int lane) {
    float tv = __shfl(bv, 63);
    int   ti = __shfl(bi, 63);
    if (__ballot(better(nv, ni, tv, ti)) == 0ULL) return;
#pragma unroll
    for (int k = 2; k <= 64; k <<= 1) {
#pragma unroll
        for (int j = k >> 1; j > 0; j >>= 1) {
            bool keepBetter = (((lane & k) == 0) == ((lane & j) == 0));
            cmp_swap(nv, ni, j, keepBetter);
        }
    }
    float rv = __shfl(nv, lane ^ 63);
    int   ri = __shfl(ni, lane ^ 63);
    if (better(rv, ri, bv, bi)) { bv = rv; bi = ri; }
#pragma unroll
    for (int j = 32; j > 0; j >>= 1) cmp_swap(bv, bi, j, (lane & j) == 0);
}

__global__ __launch_bounds__(256) void prep_weights(
    const float* __restrict__ W1, const float* __restrict__ b1,
    const float* __restrict__ W2, const float* __restrict__ b2,
    const float* __restrict__ W3, const float* __restrict__ b3,
    float* __restrict__ wbuf)
{
    int t = threadIdx.x;
    for (int i = t; i < 512; i += 256) wbuf[i] = W1[(i & 15) * 32 + (i >> 4)];
    if (t < 128) wbuf[WB_W2 + t] = W2[(t & 7) * 16 + (t >> 3)];
    if (t < 16)       wbuf[WB_B1 + t] = b1[t];
    else if (t < 24)  wbuf[WB_B2 + (t - 16)] = b2[t - 16];
    else if (t < 32)  wbuf[WB_W3 + (t - 24)] = W3[t - 24];
    else if (t == 32) wbuf[WB_B3] = b3[0];
}

// K1: pure streaming MLP — one point-quad per thread, z out.
__global__ __launch_bounds__(256, 4) void mlp_score_k1(
    const float* __restrict__ X, const float* __restrict__ wb,
    float* __restrict__ z)
{
    int q = blockIdx.x * 256 + threadIdx.x;   // quad index within batch
    if (q >= NQUAD) return;
    int b = blockIdx.y;
    int n = q * 4;
    const float* Xb = X + (size_t)b * 32 * NPTS;

    float4 a1[16];
#pragma unroll
    for (int o = 0; o < 16; ++o) a1[o] = make_float4(0.f, 0.f, 0.f, 0.f);
    // layer 1 (32->16): channel blocks of 4 float4 loads
#pragma unroll
    for (int cb = 0; cb < 8; ++cb) {
        float4 x[4];
#pragma unroll
        for (int j = 0; j < 4; ++j)
            x[j] = *reinterpret_cast<const float4*>(Xb + (size_t)(cb * 4 + j) * NPTS + n);
#pragma unroll
        for (int j = 0; j < 4; ++j) {
            int c = cb * 4 + j;
#pragma unroll
            for (int o = 0; o < 16; ++o) {
                float w = wb[c * 16 + o];          // uniform -> SGPR
                a1[o].x = fmaf(w, x[j].x, a1[o].x);
                a1[o].y = fmaf(w, x[j].y, a1[o].y);
                a1[o].z = fmaf(w, x[j].z, a1[o].z);
                a1[o].w = fmaf(w, x[j].w, a1[o].w);
            }
        }
    }
    // layer 2 (16->8) + ReLU
    float4 a2[8];
#pragma unroll
    for (int o = 0; o < 8; ++o) a2[o] = make_float4(0.f, 0.f, 0.f, 0.f);
#pragma unroll
    for (int c = 0; c < 16; ++c) {
        float bb = wb[WB_B1 + c];
        float4 h = a1[c];
        h.x = fmaxf(h.x + bb, 0.f);
        h.y = fmaxf(h.y + bb, 0.f);
        h.z = fmaxf(h.z + bb, 0.f);
        h.w = fmaxf(h.w + bb, 0.f);
#pragma unroll
        for (int o = 0; o < 8; ++o) {
            float w = wb[WB_W2 + c * 8 + o];
            a2[o].x = fmaf(w, h.x, a2[o].x);
            a2[o].y = fmaf(w, h.y, a2[o].y);
            a2[o].z = fmaf(w, h.z, a2[o].z);
            a2[o].w = fmaf(w, h.w, a2[o].w);
        }
    }
    // layer 3 (8->1) + ReLU; softplus monotone -> rank by pre-activation
    float4 zacc = make_float4(0.f, 0.f, 0.f, 0.f);
#pragma unroll
    for (int c = 0; c < 8; ++c) {
        float bb = wb[WB_B2 + c];
        float4 h = a2[c];
        h.x = fmaxf(h.x + bb, 0.f);
        h.y = fmaxf(h.y + bb, 0.f);
        h.z = fmaxf(h.z + bb, 0.f);
        h.w = fmaxf(h.w + bb, 0.f);
        float w = wb[WB_W3 + c];
        zacc.x = fmaf(w, h.x, zacc.x);
        zacc.y = fmaf(w, h.y, zacc.y);
        zacc.z = fmaf(w, h.z, zacc.z);
        zacc.w = fmaf(w, h.w, zacc.w);
    }
    float b3v = wb[WB_B3];
    zacc.x += b3v; zacc.y += b3v; zacc.z += b3v; zacc.w += b3v;
    *reinterpret_cast<float4*>(z + (size_t)b * NPTS + n) = zacc;
}

// K2: per-wave top-64 over the z array
__global__ __launch_bounds__(256) void topk_scan_k2(
    const float* __restrict__ z, int2* __restrict__ cand)
{
    int t = threadIdx.x;
    int b = blockIdx.y;
    int wave = blockIdx.x * 4 + (t >> 6);
    int lane = t & 63;
    const float* zb = z + (size_t)b * NPTS;

    float bv = -INFINITY;
    int   bi = IDX_SENTINEL;
    int waveStart = wave * PPW2;

#pragma unroll 1
    for (int r = 0; r < PPW2 / 256; ++r) {
        int n = waveStart + r * 256 + lane * 4;
        float z0 = -INFINITY, z1 = -INFINITY, z2 = -INFINITY, z3 = -INFINITY;
        bool valid = (n < NPTS);
        if (valid) {
            float4 zq = *reinterpret_cast<const float4*>(zb + n);
            z0 = zq.x; z1 = zq.y; z2 = zq.z; z3 = zq.w;
        }
        int i0 = valid ? (n + 0) : IDX_SENTINEL;
        int i1 = valid ? (n + 1) : IDX_SENTINEL;
        int i2 = valid ? (n + 2) : IDX_SENTINEL;
        int i3 = valid ? (n + 3) : IDX_SENTINEL;
        // quad-level early-out: if even max(quad) (with quad-min index for the
        // tie check) can't beat the wave's 64th-best, all 4 inserts would be
        // filtered individually — provably safe to skip.
        float m01 = fmaxf(z0, z1), m23 = fmaxf(z2, z3);
        float m = fmaxf(m01, m23);
        float tv = __shfl(bv, 63);
        int   ti = __shfl(bi, 63);
        if (__ballot(better(m, i0, tv, ti)) == 0ULL) continue;
        wave_topk_insert(bv, bi, z0, i0, lane);
        wave_topk_insert(bv, bi, z1, i1, lane);
        wave_topk_insert(bv, bi, z2, i2, lane);
        wave_topk_insert(bv, bi, z3, i3, lane);
    }

    cand[((size_t)b * LPB + wave) * 64 + lane] = make_int2(__float_as_int(bv), bi);
}

// stage A: 16 blocks/batch, 4 waves each -> reduce LPB lists to 16 lists/batch
__global__ __launch_bounds__(256) void topk_merge_k2a(
    const int2* __restrict__ cand, int2* __restrict__ cand2)
{
    __shared__ int2 sbuf[4 * 64];
    int b = blockIdx.y;
    int bk = blockIdx.x;          // 0..15
    int t = threadIdx.x;
    int w = t >> 6, lane = t & 63;
    const int2* cb = cand + (size_t)b * LPB * 64;

    float bv = -INFINITY;
    int   bi = IDX_SENTINEL;
    int slot = bk * 4 + w;        // 0..63
#pragma unroll 1
    for (int L = slot; L < LPB; L += 64) {
        int2 p = cb[(size_t)L * 64 + lane];
        wave_topk_insert(bv, bi, __int_as_float(p.x), p.y, lane);
    }
    sbuf[w * 64 + lane] = make_int2(__float_as_int(bv), bi);
    __syncthreads();

    if (w == 0) {
#pragma unroll 1
        for (int q = 1; q < 4; ++q) {
            int2 p = sbuf[q * 64 + lane];
            wave_topk_insert(bv, bi, __int_as_float(p.x), p.y, lane);
        }
        cand2[((size_t)b * 16 + bk) * 64 + lane] = make_int2(__float_as_int(bv), bi);
    }
}

// stage B: 8 blocks -> 16 lists -> final 64 indices per batch
__global__ __launch_bounds__(256) void topk_merge_k2b(
    const int2* __restrict__ cand2, int* __restrict__ out)
{
    __shared__ int2 sbuf[4 * 64];
    int b = blockIdx.x;
    int t = threadIdx.x;
    int w = t >> 6, lane = t & 63;
    const int2* cb = cand2 + (size_t)b * 16 * 64;

    int2 p0 = cb[(size_t)(w * 4) * 64 + lane];
    float bv = __int_as_float(p0.x);
    int   bi = p0.y;
#pragma unroll 1
    for (int q = 1; q < 4; ++q) {
        int2 p = cb[(size_t)(w * 4 + q) * 64 + lane];
        wave_topk_insert(bv, bi, __int_as_float(p.x), p.y, lane);
    }
    sbuf[w * 64 + lane] = make_int2(__float_as_int(bv), bi);
    __syncthreads();

    if (w == 0) {
#pragma unroll 1
        for (int q = 1; q < 4; ++q) {
            int2 p = sbuf[q * 64 + lane];
            wave_topk_insert(bv, bi, __int_as_float(p.x), p.y, lane);
        }
        out[b * K_OUT + lane] = bi;   // rank = lane (sorted desc, ties index asc)
    }
}

extern "C" void kernel_launch(void* const* d_in, const int* in_sizes, int n_in,
                              void* d_out, int out_size, void* d_ws, size_t ws_size,
                              hipStream_t stream) {
    const float* X  = (const float*)d_in[0];
    const float* W1 = (const float*)d_in[2];
    const float* b1 = (const float*)d_in[3];
    const float* W2 = (const float*)d_in[4];
    const float* b2 = (const float*)d_in[5];
    const float* W3 = (const float*)d_in[6];
    const float* b3 = (const float*)d_in[7];

    // ws layout: wbuf (4 KB) | z (8*400000 f32 = 12.8 MB) | cand | cand2
    float* wbuf  = (float*)d_ws;
    float* zbuf  = (float*)((char*)d_ws + 4096);
    int2*  cand  = (int2*)((char*)zbuf + (size_t)NBATCH * NPTS * sizeof(float));
    int2*  cand2 = cand + (size_t)NBATCH * LPB * 64;
    int*   out   = (int*)d_out;

    prep_weights<<<1, 256, 0, stream>>>(W1, b1, W2, b2, W3, b3, wbuf);
    mlp_score_k1<<<dim3((NQUAD + 255) / 256, NBATCH), 256, 0, stream>>>(X, wbuf, zbuf);
    topk_scan_k2<<<dim3(K2_BLOCKS, NBATCH), 256, 0, stream>>>(zbuf, cand);
    topk_merge_k2a<<<dim3(16, NBATCH), 256, 0, stream>>>(cand, cand2);
    topk_merge_k2b<<<dim3(NBATCH), 256, 0, stream>>>(cand2, out);
}

// Round 5
// 168.136 us; speedup vs baseline: 1.4327x; 1.4327x over previous
//
#include <hip/hip_runtime.h>
#include <math.h>

#define NPTS 400000
#define NBATCH 8
#define K_OUT 64
#define IDX_SENTINEL 0x7fffffff

#define PPW 512                       // points per wave (8 iters of 64)
#define WPB_X 196                     // blocks per batch = ceil(ceil(400000/512)/4)
#define LPB (WPB_X * 4)               // candidate lists per batch (=784)

// wbuf layout (floats): [0..511] W1^T [c][o]; [512..639] W2^T [c][o];
// [640..655] b1; [656..663] b2; [664..671] W3; [672] b3
#define WB_W2 512
#define WB_B1 640
#define WB_B2 656
#define WB_W3 664
#define WB_B3 672

// comparator: (value desc, index asc) — matches jax.lax.top_k tie-breaking
__device__ __forceinline__ bool better(float av, int ai, float bv, int bi) {
    return (av > bv) || (av == bv && ai < bi);
}

__device__ __forceinline__ void cmp_swap(float& v, int& i, int j, bool keepBetter) {
    float ov = __shfl_xor(v, j);
    int   oi = __shfl_xor(i, j);
    bool ob = better(ov, oi, v, i);
    if (keepBetter ? ob : !ob) { v = ov; i = oi; }
}

// Maintain per-wave top-64 (1 entry/lane, sorted descending by comparator).
__device__ __forceinline__ void wave_topk_insert(float& bv, int& bi, float nv, int ni, int lane) {
    float tv = __shfl(bv, 63);
    int   ti = __shfl(bi, 63);
    if (__ballot(better(nv, ni, tv, ti)) == 0ULL) return;
#pragma unroll
    for (int k = 2; k <= 64; k <<= 1) {
#pragma unroll
        for (int j = k >> 1; j > 0; j >>= 1) {
            bool keepBetter = (((lane & k) == 0) == ((lane & j) == 0));
            cmp_swap(nv, ni, j, keepBetter);
        }
    }
    float rv = __shfl(nv, lane ^ 63);
    int   ri = __shfl(ni, lane ^ 63);
    if (better(rv, ri, bv, bi)) { bv = rv; bi = ri; }
#pragma unroll
    for (int j = 32; j > 0; j >>= 1) cmp_swap(bv, bi, j, (lane & j) == 0);
}

__global__ __launch_bounds__(256) void prep_weights(
    const float* __restrict__ W1, const float* __restrict__ b1,
    const float* __restrict__ W2, const float* __restrict__ b2,
    const float* __restrict__ W3, const float* __restrict__ b3,
    float* __restrict__ wbuf)
{
    int t = threadIdx.x;
    for (int i = t; i < 512; i += 256) wbuf[i] = W1[(i & 15) * 32 + (i >> 4)];
    if (t < 128) wbuf[WB_W2 + t] = W2[(t & 7) * 16 + (t >> 3)];
    if (t < 16)       wbuf[WB_B1 + t] = b1[t];
    else if (t < 24)  wbuf[WB_B2 + (t - 16)] = b2[t - 16];
    else if (t < 32)  wbuf[WB_W3 + (t - 24)] = W3[t - 24];
    else if (t == 32) wbuf[WB_B3] = b3[0];
}

// Fused: per-thread 1 point per iter; per-wave top-64 over its PPW range.
__global__ __launch_bounds__(256, 6) void mlp_topk_fused(
    const float* __restrict__ X, const float* __restrict__ wb,
    int2* __restrict__ cand)
{
    int t = threadIdx.x;
    int b = blockIdx.y;
    int wave = blockIdx.x * 4 + (t >> 6);
    int lane = t & 63;
    const float* Xb = X + (size_t)b * 32 * NPTS;

    float bv = -INFINITY;
    int   bi = IDX_SENTINEL;
    int waveStart = wave * PPW;

#pragma unroll 1
    for (int it = 0; it < PPW / 64; ++it) {
        int nb = waveStart + it * 64;        // NPTS % 64 == 0 -> wave-uniform validity
        if (nb >= NPTS) break;
        int n = nb + lane;

        // all 32 channel loads issued up-front (independent, 32 in flight)
        float x[32];
#pragma unroll
        for (int c = 0; c < 32; ++c) x[c] = Xb[(size_t)c * NPTS + n];

        // layer 1 (32->16), c-ascending accumulation (matches reference order)
        float a1[16];
#pragma unroll
        for (int o = 0; o < 16; ++o) a1[o] = 0.f;
#pragma unroll
        for (int c = 0; c < 32; ++c) {
#pragma unroll
            for (int o = 0; o < 16; ++o)
                a1[o] = fmaf(wb[c * 16 + o], x[c], a1[o]);   // weight via SGPR
        }
        // layer 2 (16->8) + ReLU
        float a2[8];
#pragma unroll
        for (int o = 0; o < 8; ++o) a2[o] = 0.f;
#pragma unroll
        for (int c = 0; c < 16; ++c) {
            float h = fmaxf(a1[c] + wb[WB_B1 + c], 0.f);
#pragma unroll
            for (int o = 0; o < 8; ++o)
                a2[o] = fmaf(wb[WB_W2 + c * 8 + o], h, a2[o]);
        }
        // layer 3 (8->1) + ReLU; softplus monotone -> rank by pre-activation
        float z = 0.f;
#pragma unroll
        for (int c = 0; c < 8; ++c) {
            float h = fmaxf(a2[c] + wb[WB_B2 + c], 0.f);
            z = fmaf(wb[WB_W3 + c], h, z);
        }
        z += wb[WB_B3];

        wave_topk_insert(bv, bi, z, n, lane);
    }

    cand[((size_t)b * LPB + wave) * 64 + lane] = make_int2(__float_as_int(bv), bi);
}

// stage A: 16 blocks/batch, 4 waves each -> reduce LPB lists to 16 lists/batch
__global__ __launch_bounds__(256) void topk_merge_k2a(
    const int2* __restrict__ cand, int2* __restrict__ cand2)
{
    __shared__ int2 sbuf[4 * 64];
    int b = blockIdx.y;
    int bk = blockIdx.x;          // 0..15
    int t = threadIdx.x;
    int w = t >> 6, lane = t & 63;
    const int2* cb = cand + (size_t)b * LPB * 64;

    float bv = -INFINITY;
    int   bi = IDX_SENTINEL;
    int slot = bk * 4 + w;        // 0..63
#pragma unroll 1
    for (int L = slot; L < LPB; L += 64) {
        int2 p = cb[(size_t)L * 64 + lane];
        wave_topk_insert(bv, bi, __int_as_float(p.x), p.y, lane);
    }
    sbuf[w * 64 + lane] = make_int2(__float_as_int(bv), bi);
    __syncthreads();

    if (w == 0) {
#pragma unroll 1
        for (int q = 1; q < 4; ++q) {
            int2 p = sbuf[q * 64 + lane];
            wave_topk_insert(bv, bi, __int_as_float(p.x), p.y, lane);
        }
        cand2[((size_t)b * 16 + bk) * 64 + lane] = make_int2(__float_as_int(bv), bi);
    }
}

// stage B: 8 blocks -> 16 lists -> final 64 indices per batch
__global__ __launch_bounds__(256) void topk_merge_k2b(
    const int2* __restrict__ cand2, int* __restrict__ out)
{
    __shared__ int2 sbuf[4 * 64];
    int b = blockIdx.x;
    int t = threadIdx.x;
    int w = t >> 6, lane = t & 63;
    const int2* cb = cand2 + (size_t)b * 16 * 64;

    int2 p0 = cb[(size_t)(w * 4) * 64 + lane];
    float bv = __int_as_float(p0.x);
    int   bi = p0.y;
#pragma unroll 1
    for (int q = 1; q < 4; ++q) {
        int2 p = cb[(size_t)(w * 4 + q) * 64 + lane];
        wave_topk_insert(bv, bi, __int_as_float(p.x), p.y, lane);
    }
    sbuf[w * 64 + lane] = make_int2(__float_as_int(bv), bi);
    __syncthreads();

    if (w == 0) {
#pragma unroll 1
        for (int q = 1; q < 4; ++q) {
            int2 p = sbuf[q * 64 + lane];
            wave_topk_insert(bv, bi, __int_as_float(p.x), p.y, lane);
        }
        out[b * K_OUT + lane] = bi;   // rank = lane (sorted desc, ties index asc)
    }
}

extern "C" void kernel_launch(void* const* d_in, const int* in_sizes, int n_in,
                              void* d_out, int out_size, void* d_ws, size_t ws_size,
                              hipStream_t stream) {
    const float* X  = (const float*)d_in[0];
    const float* W1 = (const float*)d_in[2];
    const float* b1 = (const float*)d_in[3];
    const float* W2 = (const float*)d_in[4];
    const float* b2 = (const float*)d_in[5];
    const float* W3 = (const float*)d_in[6];
    const float* b3 = (const float*)d_in[7];

    // ws layout: wbuf (4 KB) | cand (8*784*64*8 B = 3.2 MB) | cand2 (64 KB)
    float* wbuf  = (float*)d_ws;
    int2*  cand  = (int2*)((char*)d_ws + 4096);
    int2*  cand2 = cand + (size_t)NBATCH * LPB * 64;
    int*   out   = (int*)d_out;

    prep_weights<<<1, 256, 0, stream>>>(W1, b1, W2, b2, W3, b3, wbuf);
    mlp_topk_fused<<<dim3(WPB_X, NBATCH), 256, 0, stream>>>(X, wbuf, cand);
    topk_merge_k2a<<<dim3(16, NBATCH), 256, 0, stream>>>(cand, cand2);
    topk_merge_k2b<<<dim3(NBATCH), 256, 0, stream>>>(cand2, out);
}